// Round 2
// 301.075 us; speedup vs baseline: 1.0636x; 1.0636x over previous
//
#include <hip/hip_runtime.h>

typedef __attribute__((ext_vector_type(8))) short bf16x8;
typedef __attribute__((ext_vector_type(4))) float f32x4;

__device__ __forceinline__ unsigned short f2bf(float f) {
  unsigned int u = __builtin_bit_cast(unsigned int, f);
  u += 0x7fffu + ((u >> 16) & 1u);   // round-to-nearest-even
  return (unsigned short)(u >> 16);
}

typedef const __attribute__((address_space(1))) unsigned int* as1_u32p;
typedef __attribute__((address_space(3))) unsigned int* as3_u32p;
__device__ __forceinline__ void glds16(const void* g, void* l) {
  __builtin_amdgcn_global_load_lds((as1_u32p)g, (as3_u32p)l, 16, 0, 0);
}

// ---------------------------------------------------------------------------
// K0: bulk fp32 -> bf16 convert (8 elems/thread)
// ---------------------------------------------------------------------------
__global__ __launch_bounds__(256) void cvt_kernel(const float* __restrict__ X,
                                                  unsigned short* __restrict__ Y) {
  const long long i = ((long long)blockIdx.x * 256 + threadIdx.x) * 8;
  float4 a = *reinterpret_cast<const float4*>(X + i);
  float4 b = *reinterpret_cast<const float4*>(X + i + 4);
  bf16x8 t;
  t[0] = (short)f2bf(a.x); t[1] = (short)f2bf(a.y);
  t[2] = (short)f2bf(a.z); t[3] = (short)f2bf(a.w);
  t[4] = (short)f2bf(b.x); t[5] = (short)f2bf(b.y);
  t[6] = (short)f2bf(b.z); t[7] = (short)f2bf(b.w);
  *reinterpret_cast<bf16x8*>(Y + i) = t;
}

// ---------------------------------------------------------------------------
// K0t: fp32 [R][C] -> bf16 [C][R] transpose (32x32 tiles)
// ---------------------------------------------------------------------------
__global__ __launch_bounds__(256) void transpose_bf16_kernel(
    const float* __restrict__ S, unsigned short* __restrict__ D, int R, int C) {
  __shared__ float T[32][33];
  const int bx = blockIdx.x * 32;  // col tile
  const int by = blockIdx.y * 32;  // row tile
  const int tx = threadIdx.x & 31, ty = threadIdx.x >> 5;
#pragma unroll
  for (int k = 0; k < 4; ++k)
    T[ty + 8 * k][tx] = S[(size_t)(by + ty + 8 * k) * C + bx + tx];
  __syncthreads();
#pragma unroll
  for (int k = 0; k < 4; ++k)
    D[(size_t)(bx + ty + 8 * k) * R + by + tx] = f2bf(T[tx][ty + 8 * k]);
}

// ---------------------------------------------------------------------------
// K0m: mask bit-pack.  Mb[(s*256+row)*16 + l] : bit ct = mask[s][row][ct*16+l]
// 512 KiB total -> L2/L3 resident; attn reads ONE u16 per (row,lane) instead
// of 16 strided dword loads.
// ---------------------------------------------------------------------------
__global__ __launch_bounds__(256) void pack_mask_kernel(const int* __restrict__ mask,
                                                        unsigned short* __restrict__ Mb) {
  const int t = blockIdx.x * 256 + threadIdx.x;  // (s*256+row)*16 + l
  const int l = t & 15;
  const int r = t >> 4;                          // s*256 + row
  const int* mp = mask + ((size_t)r << 8) + l;
  unsigned int bits = 0;
#pragma unroll
  for (int ct = 0; ct < 16; ++ct)
    bits |= (mp[ct << 4] != 0 ? (1u << ct) : 0u);
  Mb[t] = (unsigned short)bits;
}

// ---------------------------------------------------------------------------
// K1/K3: bf16 GEMM  C[M][N] = A[M][K] * Bt[N][K]^T (+bias), fp32 accum.
// m97-style: 128x128 tile, BK=32, global_load_lds width-16 staging into
// UNPADDED contiguous LDS (stride 32 shorts), 16 MFMA/wave/K-step.
// ---------------------------------------------------------------------------
template <bool C_F32>
__global__ __launch_bounds__(256) void gemm_bt(
    const unsigned short* __restrict__ A,   // [M][K] bf16
    const unsigned short* __restrict__ Bt,  // [N][K] bf16
    void* __restrict__ Cv,
    const float* __restrict__ bias,         // [N] fp32 (C_F32 only)
    int M, int N, int K)
{
  __shared__ __align__(16) unsigned short As[128 * 32];  // unpadded (GLDS layout)
  __shared__ __align__(16) unsigned short Bs[128 * 32];

  const int tid  = threadIdx.x;
  const int bm   = blockIdx.x * 128;
  const int bn   = blockIdx.y * 128;
  const int lane = tid & 63;
  const int wave = tid >> 6;
  const int wr   = (wave >> 1) * 64;
  const int wc   = (wave & 1) * 64;
  const int l15  = lane & 15;
  const int quad = lane >> 4;

  f32x4 acc[4][4];
#pragma unroll
  for (int r = 0; r < 4; ++r)
#pragma unroll
    for (int c = 0; c < 4; ++c) {
      f32x4 z = {0.f, 0.f, 0.f, 0.f};
      acc[r][c] = z;
    }

  // per-lane global srcs; wave-uniform LDS dests (dest = base + lane*16B)
  const unsigned short* gA0 = A  + (size_t)(bm + wave * 16 + (lane >> 2)) * K + (lane & 3) * 8;
  const unsigned short* gA1 = gA0 + (size_t)64 * K;
  const unsigned short* gB0 = Bt + (size_t)(bn + wave * 16 + (lane >> 2)) * K + (lane & 3) * 8;
  const unsigned short* gB1 = gB0 + (size_t)64 * K;
  unsigned short* lA0 = As + wave * 512;
  unsigned short* lA1 = As + 2048 + wave * 512;
  unsigned short* lB0 = Bs + wave * 512;
  unsigned short* lB1 = Bs + 2048 + wave * 512;

  for (int kk = 0; kk < K; kk += 32) {
    glds16(gA0 + kk, lA0);
    glds16(gA1 + kk, lA1);
    glds16(gB0 + kk, lB0);
    glds16(gB1 + kk, lB1);
    __syncthreads();   // drains vmcnt before barrier (compiler-enforced)

    bf16x8 af[4], bf[4];
#pragma unroll
    for (int i = 0; i < 4; ++i) {
      af[i] = *reinterpret_cast<const bf16x8*>(&As[(wr + i * 16 + l15) * 32 + quad * 8]);
      bf[i] = *reinterpret_cast<const bf16x8*>(&Bs[(wc + i * 16 + l15) * 32 + quad * 8]);
    }
#pragma unroll
    for (int rt = 0; rt < 4; ++rt)
#pragma unroll
      for (int ct = 0; ct < 4; ++ct)
        acc[rt][ct] = __builtin_amdgcn_mfma_f32_16x16x32_bf16(af[rt], bf[ct], acc[rt][ct], 0, 0, 0);
    __syncthreads();
  }

  // epilogue: D[row=quad*4+i][col=l15] per 16x16 tile (proven layout)
#pragma unroll
  for (int rt = 0; rt < 4; ++rt)
#pragma unroll
    for (int ct = 0; ct < 4; ++ct)
#pragma unroll
      for (int i = 0; i < 4; ++i) {
        const int row = bm + wr + rt * 16 + quad * 4 + i;
        const int col = bn + wc + ct * 16 + l15;
        const float v = acc[rt][ct][i];
        if constexpr (C_F32) {
          ((float*)Cv)[(size_t)row * N + col] = v + bias[col];
        } else {
          ((unsigned short*)Cv)[(size_t)row * N + col] = f2bf(v);
        }
      }
}

// ---------------------------------------------------------------------------
// K2: masked softmax attention.
//  - mask via bit-packed Mb (1 u16 load per (qb,i) instead of 16 dword loads)
//  - Ks: unpadded [256][32] + XOR-granule swizzle (g ^= (row>>1)&3): 16 KiB
//  - V stage stride 38 shorts: quads land on distinct bank ranges
//    ({0,24,16,8}+[0..7]) -> conflict-free gather.  Staged via 16 word-wise
//    (4B) copies: base tid*76 B is 4B-aligned, NOT 16B-aligned.
//  - LDS 56320 -> 52224 B  => 3 blocks/CU (was 2)
// ---------------------------------------------------------------------------
#define SCALE_F 0.17677669529663689f

__global__ __launch_bounds__(256) void attn_kernel(
    const unsigned short* __restrict__ QKV,   // [t][768] bf16: Q|K|V
    const unsigned short* __restrict__ Mb,    // [64*256][16] u16 bit-packed mask
    unsigned short* __restrict__ Aout)        // [65536][256] bf16
{
  __shared__ __align__(16) unsigned short Ks[256 * 32];      // swizzled, 16384 B
  __shared__ __align__(16) unsigned short SH[4 * 16 * 280];  // P per wave; V stage at init

  const int blk  = blockIdx.x;   // 0..2047
  const int h    = blk & 7;
  const int sb   = blk >> 3;
  const int s    = sb >> 2;
  const int t0   = sb << 8;
  const int tid  = threadIdx.x;
  const int lane = tid & 63;
  const int wave = tid >> 6;
  const int l15  = lane & 15;
  const int quad = lane >> 4;

  {
    const unsigned short* kp = QKV + (size_t)(t0 + tid) * 768 + 256 + h * 32;
    const unsigned short* vp = kp + 256;
    const int sw = (tid >> 1) & 3;              // row-granule swizzle
    unsigned short* kd = Ks + tid * 32;
    unsigned short* vd = SH + tid * 38;
#pragma unroll
    for (int g = 0; g < 4; ++g)
      *reinterpret_cast<uint4*>(kd + ((g ^ sw) << 3)) = *reinterpret_cast<const uint4*>(kp + g * 8);
#pragma unroll
    for (int i = 0; i < 16; ++i)   // 16 x 4B word copies: covers all 32 shorts
      *reinterpret_cast<unsigned int*>(vd + i * 2) = *reinterpret_cast<const unsigned int*>(vp + i * 2);
  }
  __syncthreads();

  bf16x8 bv[2][8];
#pragma unroll
  for (int dt = 0; dt < 2; ++dt)
#pragma unroll
    for (int ks = 0; ks < 8; ++ks) {
      bf16x8 v;
#pragma unroll
      for (int j = 0; j < 8; ++j)
        v[j] = (short)SH[(ks * 32 + quad * 8 + j) * 38 + dt * 16 + l15];
      bv[dt][ks] = v;
    }
  __syncthreads();   // V stage region now free -> P

  unsigned short* P = SH + wave * (16 * 280);
  const int swr = (l15 >> 1) & 3;   // K-read granule swizzle (row = ct*16+l15)

  for (int qb = 0; qb < 4; ++qb) {
    const int qbase = wave * 64 + qb * 16;

    bf16x8 qf = *reinterpret_cast<const bf16x8*>(
        QKV + (size_t)(t0 + qbase + l15) * 768 + h * 32 + quad * 8);

    // bit-packed mask: one u16 per output row (hoisted to overlap MFMA)
    unsigned short mbits[4];
#pragma unroll
    for (int i = 0; i < 4; ++i)
      mbits[i] = Mb[(((size_t)s << 12)) + ((size_t)(qbase + quad * 4 + i) << 4) + l15];

    f32x4 sim[16];
#pragma unroll
    for (int ct = 0; ct < 16; ++ct) {
      bf16x8 kf = *reinterpret_cast<const bf16x8*>(
          &Ks[(ct * 16 + l15) * 32 + ((quad ^ swr) << 3)]);
      f32x4 z = {0.f, 0.f, 0.f, 0.f};
      sim[ct] = __builtin_amdgcn_mfma_f32_16x16x32_bf16(qf, kf, z, 0, 0, 0);
    }

    float lsum[4];
#pragma unroll
    for (int i = 0; i < 4; ++i) {
      const unsigned int mw = mbits[i];
      float mx = -3.0e38f;
#pragma unroll
      for (int ct = 0; ct < 16; ++ct) {
        float v = sim[ct][i] * SCALE_F;
        if (!((mw >> ct) & 1u)) v = -1.0e10f;
        sim[ct][i] = v;
        mx = fmaxf(mx, v);
      }
#pragma unroll
      for (int off = 1; off < 16; off <<= 1)
        mx = fmaxf(mx, __shfl_xor(mx, off, 64));
      float sum = 0.f;
#pragma unroll
      for (int ct = 0; ct < 16; ++ct) {
        float e = __expf(sim[ct][i] - mx);
        sim[ct][i] = e;
        sum += e;
      }
#pragma unroll
      for (int off = 1; off < 16; off <<= 1)
        sum += __shfl_xor(sum, off, 64);
      lsum[i] = sum;
    }

#pragma unroll
    for (int i = 0; i < 4; ++i)
#pragma unroll
      for (int ct = 0; ct < 16; ++ct)
        P[(quad * 4 + i) * 280 + ct * 16 + l15] = f2bf(sim[ct][i]);
    __syncthreads();

    f32x4 o0 = {0.f, 0.f, 0.f, 0.f};
    f32x4 o1 = {0.f, 0.f, 0.f, 0.f};
#pragma unroll
    for (int ks = 0; ks < 8; ++ks) {
      bf16x8 pf = *reinterpret_cast<const bf16x8*>(&P[l15 * 280 + ks * 32 + quad * 8]);
      o0 = __builtin_amdgcn_mfma_f32_16x16x32_bf16(pf, bv[0][ks], o0, 0, 0, 0);
      o1 = __builtin_amdgcn_mfma_f32_16x16x32_bf16(pf, bv[1][ks], o1, 0, 0, 0);
    }

#pragma unroll
    for (int i = 0; i < 4; ++i) {
      const float rl = 1.0f / lsum[i];
      const size_t row = (size_t)t0 + qbase + quad * 4 + i;
      Aout[row * 256 + h * 32 + l15]      = f2bf(o0[i] * rl);
      Aout[row * 256 + h * 32 + 16 + l15] = f2bf(o1[i] * rl);
    }
    __syncthreads();
  }
}

// ---------------------------------------------------------------------------
// Memory plan:
//   ws[0, 96MiB)        QKV  (live K1->attn); WoutT transposed into ws[0]
//                             AFTER attn (QKV dead) for K3.
//   ws[96MiB, 128MiB)   Xbf  (live cvt->K1), then Amid aliases it (attn->K3).
//   d_out[0, 384KB)     WqkvT scratch (live ->K1; K1 only READS d_out).
//   d_out[32MiB, 32.5MiB) Mbits bit-packed mask (live pack->attn).
//   K3 overwrites all of d_out at the end.
// ---------------------------------------------------------------------------
extern "C" void kernel_launch(void* const* d_in, const int* in_sizes, int n_in,
                              void* d_out, int out_size, void* d_ws, size_t ws_size,
                              hipStream_t stream) {
  const float* X    = (const float*)d_in[0];  // [65536][256] fp32
  const int*   mask = (const int*)d_in[1];    // [64][256][256] int32
  const float* Wqkv = (const float*)d_in[2];  // [256][768] fp32
  const float* Wout = (const float*)d_in[3];  // [256][256] fp32
  const float* bout = (const float*)d_in[4];  // [256] fp32
  float*       outp = (float*)d_out;          // [65536][256] fp32

  unsigned short* QKV   = (unsigned short*)d_ws;       // 96 MiB
  unsigned short* Xbf   = QKV + (size_t)65536 * 768;   // 32 MiB
  unsigned short* Amid  = Xbf;                         // alias: Xbf dead after K1
  unsigned short* WoutT = QKV;                         // alias: QKV dead after attn
  unsigned short* WqkvT = (unsigned short*)d_out;      // d_out scratch, dead before K3
  unsigned short* Mbits = (unsigned short*)d_out + ((size_t)16 << 20);  // d_out + 32 MiB

  dim3 blk(256);
  cvt_kernel<<<dim3(8192), blk, 0, stream>>>(X, Xbf);
  transpose_bf16_kernel<<<dim3(24, 8), blk, 0, stream>>>(Wqkv, WqkvT, 256, 768);
  pack_mask_kernel<<<dim3(1024), blk, 0, stream>>>(mask, Mbits);

  gemm_bt<false><<<dim3(512, 6), blk, 0, stream>>>(Xbf, WqkvT, (void*)QKV, nullptr, 65536, 768, 256);
  attn_kernel<<<dim3(2048), blk, 0, stream>>>(QKV, Mbits, Amid);

  transpose_bf16_kernel<<<dim3(8, 8), blk, 0, stream>>>(Wout, WoutT, 256, 256);
  gemm_bt<true><<<dim3(512, 2), blk, 0, stream>>>(Amid, WoutT, (void*)outp, bout, 65536, 256, 256);
}